// Round 3
// baseline (561.462 us; speedup 1.0000x reference)
//
#include <hip/hip_runtime.h>
#include <hip/hip_bf16.h>
#include <stdint.h>
#include <stddef.h>

// LinearMoE: B=4096 tokens, D=2048, H=2048, E=8, K=2.  fp32 in/out.
#define B_TOK 4096
#define D_DIM 2048
#define H_DIM 2048
#define E_NUM 8

typedef __bf16 bf16;
typedef __attribute__((ext_vector_type(8))) __bf16 bf16x8;
typedef __attribute__((ext_vector_type(4))) float f32x4;

// ---------------- ws layout ----------------
// [0,32)            counts[8] int
// [4096,135168)     entries[8][4096] int   value=(token<<1)|slot
// [135168,167936)   tk_idx[4096][2] int
// [167936,200704)   tk_w[4096][2] float
// fast path only:
// [262144, +16.78M) xbf [4096][2048] bf16
// [17039360, +67.1M) WeT [8][2048][2048] bf16 (h-major, d-contiguous)
#define WS_COUNTS   0
#define WS_ENTRIES  4096
#define WS_TKIDX    135168
#define WS_TKW      167936
#define WS_XBF      262144
#define WS_WET      17039360
#define WS_BIG_NEED 84148224ULL

__device__ __forceinline__ void gload16(const void* g, void* l) {
  __builtin_amdgcn_global_load_lds(
      (const __attribute__((address_space(1))) void*)g,
      (__attribute__((address_space(3))) void*)l, 16, 0, 0);
}

__global__ void zero_counts(int* counts) {
  if (threadIdx.x < E_NUM) counts[threadIdx.x] = 0;
}

// One wave per token. fp64 accumulation so top-2 ordering matches np ref.
__global__ void gating_kernel(const float* __restrict__ x,
                              const float* __restrict__ Wg,
                              const float* __restrict__ bg,
                              int* counts, int* entries,
                              int* tk_idx, float* tk_w) {
  int gtid = blockIdx.x * blockDim.x + threadIdx.x;
  int b = gtid >> 6;
  int lane = threadIdx.x & 63;
  if (b >= B_TOK) return;
  const float* xrow = x + (size_t)b * D_DIM;

  double acc[E_NUM];
#pragma unroll
  for (int e = 0; e < E_NUM; e++) acc[e] = 0.0;

#pragma unroll
  for (int i = 0; i < 8; i++) {
    int d0 = i * 256 + lane * 4;
    f32x4 xv = *(const f32x4*)(xrow + d0);
#pragma unroll
    for (int j = 0; j < 4; j++) {
      double xf = (double)xv[j];
      f32x4 w0 = *(const f32x4*)(Wg + (size_t)(d0 + j) * E_NUM);
      f32x4 w1 = *(const f32x4*)(Wg + (size_t)(d0 + j) * E_NUM + 4);
#pragma unroll
      for (int e = 0; e < 4; e++) acc[e] += xf * (double)w0[e];
#pragma unroll
      for (int e = 0; e < 4; e++) acc[4 + e] += xf * (double)w1[e];
    }
  }
#pragma unroll
  for (int e = 0; e < E_NUM; e++) {
    double v = acc[e];
#pragma unroll
    for (int off = 32; off >= 1; off >>= 1) v += __shfl_xor(v, off, 64);
    acc[e] = v;
  }

  if (lane == 0) {
    double lg[E_NUM];
#pragma unroll
    for (int e = 0; e < E_NUM; e++) lg[e] = acc[e] + (double)bg[e];
    int i0 = 0; double v0 = lg[0];
#pragma unroll
    for (int e = 1; e < E_NUM; e++) if (lg[e] > v0) { v0 = lg[e]; i0 = e; }
    int i1 = -1; double v1 = -1e300;
#pragma unroll
    for (int e = 0; e < E_NUM; e++)
      if (e != i0 && lg[e] > v1) { v1 = lg[e]; i1 = e; }
    double m = v0;  // v0 is the max
    double den = 0.0;
    double p0 = 0.0, p1 = 0.0;
#pragma unroll
    for (int e = 0; e < E_NUM; e++) {
      double pe = exp(lg[e] - m);
      den += pe;
      if (e == i0) p0 = pe;
      if (e == i1) p1 = pe;
    }
    tk_idx[2 * b] = i0;
    tk_idx[2 * b + 1] = i1;
    tk_w[2 * b] = (float)(p0 / den);
    tk_w[2 * b + 1] = (float)(p1 / den);
    int q0 = atomicAdd(&counts[i0], 1);
    entries[i0 * B_TOK + q0] = (b << 1);
    int q1 = atomicAdd(&counts[i1], 1);
    entries[i1 * B_TOK + q1] = (b << 1) | 1;
  }
}

// out[b][h] = w0*be[e0][h] + w1*be[e1][h]  (overwrites poison; GEMM atomics add on top)
__global__ void prefill_kernel(const float* __restrict__ be,
                               const int* __restrict__ tk_idx,
                               const float* __restrict__ tk_w,
                               float* __restrict__ out) {
  int idx = blockIdx.x * blockDim.x + threadIdx.x;  // B*H/4 threads
  int b = idx >> 9;
  int hc = (idx & 511) * 4;
  int e0 = tk_idx[2 * b], e1 = tk_idx[2 * b + 1];
  float w0 = tk_w[2 * b], w1 = tk_w[2 * b + 1];
  f32x4 b0 = *(const f32x4*)(be + (size_t)e0 * H_DIM + hc);
  f32x4 b1 = *(const f32x4*)(be + (size_t)e1 * H_DIM + hc);
  f32x4 o;
#pragma unroll
  for (int j = 0; j < 4; j++) o[j] = w0 * b0[j] + w1 * b1[j];
  *(f32x4*)(out + (size_t)b * H_DIM + hc) = o;
}

// ---- fast path helpers ----
__global__ void xcvt_kernel(const float* __restrict__ x, bf16* __restrict__ xbf) {
  int idx = blockIdx.x * blockDim.x + threadIdx.x;  // B*D/8 threads
  f32x4 a = *(const f32x4*)(x + (size_t)idx * 8);
  f32x4 c = *(const f32x4*)(x + (size_t)idx * 8 + 4);
  bf16x8 o;
#pragma unroll
  for (int j = 0; j < 4; j++) { o[j] = (bf16)a[j]; o[4 + j] = (bf16)c[j]; }
  *(bf16x8*)(xbf + (size_t)idx * 8) = o;
}

// We[e][d][h] fp32 -> WeT[e][h][d] bf16, 64x64 tiles.
// Read: per wave 16 rows x 256B contiguous segments.
// Write: per wave 8 rows x 128B contiguous segments (fully coalesced 16B/lane).
// LDS: tile[64][65] -> both phases only 2-way bank aliasing (free per m136).
__global__ void transpose_cvt_we(const float* __restrict__ We, bf16* __restrict__ WeT) {
  __shared__ __align__(16) float tile[64][65];
  int e = blockIdx.z;
  int h0 = blockIdx.x * 64, d0 = blockIdx.y * 64;
  int t = threadIdx.x;
  int dr = t >> 2, hc = (t & 3) * 16;
  const float* src = We + ((size_t)e * D_DIM + d0 + dr) * H_DIM + h0 + hc;
#pragma unroll
  for (int i = 0; i < 4; i++)
    *(f32x4*)(&tile[dr][hc + 4 * i]) = *(const f32x4*)(src + 4 * i);
  __syncthreads();
  int hh = t >> 3, dp = (t & 7) * 8;
  bf16* dste = WeT + (size_t)e * H_DIM * D_DIM;
#pragma unroll
  for (int s = 0; s < 2; s++) {
    int h = hh + 32 * s;
    bf16x8 v;
#pragma unroll
    for (int j = 0; j < 8; j++) v[j] = (bf16)tile[dp + j][h];
    *(bf16x8*)(dste + (size_t)(h0 + h) * D_DIM + d0 + dp) = v;
  }
}

// LDS fragment layout: chunk ci (16 rows), lane l holds A[m=16ci+(l&15)][k=8*(l>>4)+j]
// -> staging dst = base + l*16B (wave-uniform base, matches global_load_lds semantics)
// -> fragment read: lane l reads ci*1024B + l*16B (contiguous, conflict-free)

// Distance-2 software pipeline, 3 LDS buffers, raw s_barrier + vmcnt(4):
// at top of iter k: outstanding = k's 4 + (k+1)'s 4 loads per wave. vmcnt(4)
// completes k's; s_barrier then proves ALL waves' k-loads landed AND all waves
// finished reading buf[(k-1)%3] (== buf[(k+2)%3]) during iter k-1, so issuing
// k+2 into that buffer after the barrier is race-free.
__global__ __launch_bounds__(256) void moe_gemm_fast(
    const bf16* __restrict__ xbf, const bf16* __restrict__ WeT,
    const int* __restrict__ counts, const int* __restrict__ entries,
    const float* __restrict__ tk_w, float* __restrict__ out) {
  __shared__ __align__(16) bf16 As_s[3 * 4096];
  __shared__ __align__(16) bf16 Bs_s[3 * 4096];
  int e = blockIdx.y >> 5, mtile = blockIdx.y & 31;
  int cnt = counts[e];
  if (mtile * 128 >= cnt) return;
  int n0 = blockIdx.x * 128;
  int tid = threadIdx.x, lane = tid & 63, w = tid >> 6;
  int r = lane & 15, q = lane >> 4;
  const int* ereg = entries + e * B_TOK;
  const bf16* wet_e = WeT + (size_t)e * H_DIM * D_DIM;

  const bf16* srcA[2]; const bf16* srcB[2];
  int chunk_off[2];
#pragma unroll
  for (int j = 0; j < 2; j++) {
    int ci = w * 2 + j;
    int m = mtile * 128 + 16 * ci + r;
    int tok = ereg[min(m, cnt - 1)] >> 1;
    srcA[j] = xbf + (size_t)tok * D_DIM + 8 * q;
    srcB[j] = wet_e + (size_t)(n0 + 16 * ci + r) * D_DIM + 8 * q;
    chunk_off[j] = ci * 512;
  }
  int wm4 = (w & 1) * 4, wn4 = (w >> 1) * 4;

  f32x4 acc[4][4];
#pragma unroll
  for (int i = 0; i < 4; i++)
#pragma unroll
    for (int j = 0; j < 4; j++) acc[i][j] = (f32x4){0.f, 0.f, 0.f, 0.f};

  // prologue: issue tiles 0 and 1
#pragma unroll
  for (int p = 0; p < 2; p++) {
#pragma unroll
    for (int j = 0; j < 2; j++) {
      gload16(srcA[j] + p * 32, As_s + p * 4096 + chunk_off[j]);
      gload16(srcB[j] + p * 32, Bs_s + p * 4096 + chunk_off[j]);
    }
  }

  int pc = 0;      // buffer holding tile `it`
  int pb = 2;      // buffer to receive tile `it+2`
  for (int it = 0; it < 63; it++) {
    asm volatile("s_waitcnt vmcnt(4)\n\ts_barrier" ::: "memory");
    if (it < 62) {
      int kk = (it + 2) * 32;
#pragma unroll
      for (int j = 0; j < 2; j++) {
        gload16(srcA[j] + kk, As_s + pb * 4096 + chunk_off[j]);
        gload16(srcB[j] + kk, Bs_s + pb * 4096 + chunk_off[j]);
      }
    }
    {
      const bf16* Ab = As_s + pc * 4096;
      const bf16* Bb = Bs_s + pc * 4096;
      bf16x8 af[4], bfr[4];
#pragma unroll
      for (int i = 0; i < 4; i++)
        af[i] = *(const bf16x8*)(Ab + (wm4 + i) * 512 + lane * 8);
#pragma unroll
      for (int j = 0; j < 4; j++)
        bfr[j] = *(const bf16x8*)(Bb + (wn4 + j) * 512 + lane * 8);
#pragma unroll
      for (int i = 0; i < 4; i++)
#pragma unroll
        for (int j = 0; j < 4; j++)
          acc[i][j] = __builtin_amdgcn_mfma_f32_16x16x32_bf16(af[i], bfr[j],
                                                              acc[i][j], 0, 0, 0);
    }
    pc = (pc == 2) ? 0 : pc + 1;
    pb = (pb == 2) ? 0 : pb + 1;
  }
  // final iteration: wait everything
  asm volatile("s_waitcnt vmcnt(0)\n\ts_barrier" ::: "memory");
  {
    const bf16* Ab = As_s + pc * 4096;
    const bf16* Bb = Bs_s + pc * 4096;
    bf16x8 af[4], bfr[4];
#pragma unroll
    for (int i = 0; i < 4; i++)
      af[i] = *(const bf16x8*)(Ab + (wm4 + i) * 512 + lane * 8);
#pragma unroll
    for (int j = 0; j < 4; j++)
      bfr[j] = *(const bf16x8*)(Bb + (wn4 + j) * 512 + lane * 8);
#pragma unroll
    for (int i = 0; i < 4; i++)
#pragma unroll
      for (int j = 0; j < 4; j++)
        acc[i][j] = __builtin_amdgcn_mfma_f32_16x16x32_bf16(af[i], bfr[j],
                                                            acc[i][j], 0, 0, 0);
  }

  int base_r = mtile * 128, wm = (w & 1) * 64, wn = (w >> 1) * 64;
#pragma unroll
  for (int i = 0; i < 4; i++)
#pragma unroll
    for (int reg = 0; reg < 4; reg++) {
      int rg = base_r + wm + 16 * i + q * 4 + reg;
      if (rg < cnt) {
        int ent = ereg[rg];
        int tok = ent >> 1, slot = ent & 1;
        float wgt = tk_w[2 * tok + slot];
        float* orow = out + (size_t)tok * H_DIM + n0 + wn;
#pragma unroll
        for (int j = 0; j < 4; j++)
          atomicAdd(orow + 16 * j + r, wgt * acc[i][j][reg]);
      }
    }
}

// Small-ws fallback path (unchanged): A gathered per-thread fp32->bf16; B staged
// raw fp32 via global_load_lds then transposed+converted each K-iter.
__global__ __launch_bounds__(256) void moe_gemm_slow(
    const float* __restrict__ x, const float* __restrict__ We,
    const int* __restrict__ counts, const int* __restrict__ entries,
    const float* __restrict__ tk_w, float* __restrict__ out) {
  __shared__ __align__(16) bf16 As_f[4096];
  __shared__ __align__(16) bf16 Bs_f[4096];
  __shared__ __align__(16) float Braw[4096];  // [k<32][n<128]
  int e = blockIdx.y >> 5, mtile = blockIdx.y & 31;
  int cnt = counts[e];
  if (mtile * 128 >= cnt) return;
  int n0 = blockIdx.x * 128;
  int tid = threadIdx.x, lane = tid & 63, w = tid >> 6;
  int r = lane & 15, q = lane >> 4;
  const int* ereg = entries + e * B_TOK;

  const float* srcA[2]; bf16* dstA[2];
#pragma unroll
  for (int s = 0; s < 2; s++) {
    int c = tid + s * 256;
    int ci = c >> 6, qq = (c >> 4) & 3, rr = c & 15;
    int m = mtile * 128 + 16 * ci + rr;
    int tok = ereg[min(m, cnt - 1)] >> 1;
    srcA[s] = x + (size_t)tok * D_DIM + 8 * qq;
    dstA[s] = As_f + c * 8;
  }
  const float* srcBr[4]; float* dstBr[4];
#pragma unroll
  for (int i = 0; i < 4; i++) {
    int row = (w * 4 + i) * 2 + (lane >> 5);
    srcBr[i] = We + ((size_t)e * D_DIM + row) * H_DIM + n0 + (lane & 31) * 4;
    dstBr[i] = Braw + (w * 4 + i) * 256;
  }
  int n2[2], q2[2]; bf16* dstB2[2];
#pragma unroll
  for (int s = 0; s < 2; s++) {
    int c = tid + s * 256;
    n2[s] = 16 * (c >> 6) + (c & 15);
    q2[s] = (c >> 4) & 3;
    dstB2[s] = Bs_f + c * 8;
  }
  int wm4 = (w & 1) * 4, wn4 = (w >> 1) * 4;

  f32x4 acc[4][4];
#pragma unroll
  for (int i = 0; i < 4; i++)
#pragma unroll
    for (int j = 0; j < 4; j++) acc[i][j] = (f32x4){0.f, 0.f, 0.f, 0.f};

  for (int k0 = 0; k0 < D_DIM; k0 += 32) {
    __syncthreads();
#pragma unroll
    for (int i = 0; i < 4; i++)
      gload16(srcBr[i] + (size_t)k0 * H_DIM, dstBr[i]);
#pragma unroll
    for (int s = 0; s < 2; s++) {
      f32x4 a0 = *(const f32x4*)(srcA[s] + k0);
      f32x4 a1 = *(const f32x4*)(srcA[s] + k0 + 4);
      bf16x8 av;
#pragma unroll
      for (int j = 0; j < 4; j++) { av[j] = (bf16)a0[j]; av[4 + j] = (bf16)a1[j]; }
      *(bf16x8*)dstA[s] = av;
    }
    __syncthreads();
#pragma unroll
    for (int s = 0; s < 2; s++) {
      bf16x8 bv;
#pragma unroll
      for (int t2 = 0; t2 < 8; t2++)
        bv[t2] = (bf16)Braw[(8 * q2[s] + t2) * 128 + n2[s]];
      *(bf16x8*)dstB2[s] = bv;
    }
    __syncthreads();
    bf16x8 af[4], bfr[4];
#pragma unroll
    for (int i = 0; i < 4; i++)
      af[i] = *(const bf16x8*)(As_f + (wm4 + i) * 512 + lane * 8);
#pragma unroll
    for (int j = 0; j < 4; j++)
      bfr[j] = *(const bf16x8*)(Bs_f + (wn4 + j) * 512 + lane * 8);
#pragma unroll
    for (int i = 0; i < 4; i++)
#pragma unroll
      for (int j = 0; j < 4; j++)
        acc[i][j] = __builtin_amdgcn_mfma_f32_16x16x32_bf16(af[i], bfr[j],
                                                            acc[i][j], 0, 0, 0);
  }

  int base_r = mtile * 128, wm = (w & 1) * 64, wn = (w >> 1) * 64;
#pragma unroll
  for (int i = 0; i < 4; i++)
#pragma unroll
    for (int reg = 0; reg < 4; reg++) {
      int rg = base_r + wm + 16 * i + q * 4 + reg;
      if (rg < cnt) {
        int ent = ereg[rg];
        int tok = ent >> 1, slot = ent & 1;
        float wgt = tk_w[2 * tok + slot];
        float* orow = out + (size_t)tok * H_DIM + n0 + wn;
#pragma unroll
        for (int j = 0; j < 4; j++)
          atomicAdd(orow + 16 * j + r, wgt * acc[i][j][reg]);
      }
    }
}

extern "C" void kernel_launch(void* const* d_in, const int* in_sizes, int n_in,
                              void* d_out, int out_size, void* d_ws, size_t ws_size,
                              hipStream_t stream) {
  const float* x  = (const float*)d_in[0];
  const float* Wg = (const float*)d_in[1];
  const float* bg = (const float*)d_in[2];
  const float* We = (const float*)d_in[3];
  const float* be = (const float*)d_in[4];
  float* out = (float*)d_out;

  char* ws = (char*)d_ws;
  int*   counts  = (int*)(ws + WS_COUNTS);
  int*   entries = (int*)(ws + WS_ENTRIES);
  int*   tk_idx  = (int*)(ws + WS_TKIDX);
  float* tk_w    = (float*)(ws + WS_TKW);
  bf16*  xbf     = (bf16*)(ws + WS_XBF);
  bf16*  WeT     = (bf16*)(ws + WS_WET);

  bool big = (ws_size >= WS_BIG_NEED);

  hipLaunchKernelGGL(zero_counts, dim3(1), dim3(64), 0, stream, counts);
  hipLaunchKernelGGL(gating_kernel, dim3(B_TOK / 4), dim3(256), 0, stream,
                     x, Wg, bg, counts, entries, tk_idx, tk_w);
  hipLaunchKernelGGL(prefill_kernel, dim3(B_TOK * H_DIM / 4 / 256), dim3(256), 0,
                     stream, be, tk_idx, tk_w, out);
  if (big) {
    hipLaunchKernelGGL(xcvt_kernel, dim3(B_TOK * D_DIM / 8 / 256), dim3(256), 0,
                       stream, x, xbf);
    hipLaunchKernelGGL(transpose_cvt_we, dim3(H_DIM / 64, D_DIM / 64, E_NUM),
                       dim3(256), 0, stream, We, WeT);
    hipLaunchKernelGGL(moe_gemm_fast, dim3(H_DIM / 128, E_NUM * 32), dim3(256), 0,
                       stream, xbf, WeT, counts, entries, tk_w, out);
  } else {
    hipLaunchKernelGGL(moe_gemm_slow, dim3(H_DIM / 128, E_NUM * 32), dim3(256), 0,
                       stream, x, We, counts, entries, tk_w, out);
  }
}

// Round 5
// 522.234 us; speedup vs baseline: 1.0751x; 1.0751x over previous
//
#include <hip/hip_runtime.h>
#include <hip/hip_bf16.h>
#include <stdint.h>
#include <stddef.h>

// LinearMoE: B=4096 tokens, D=2048, H=2048, E=8, K=2.  fp32 in/out.
#define B_TOK 4096
#define D_DIM 2048
#define H_DIM 2048
#define E_NUM 8
#define MAX_SLOTS 72   // sum over experts of ceil(cnt/128) <= 64+7

typedef __bf16 bf16;
typedef __attribute__((ext_vector_type(8))) __bf16 bf16x8;
typedef __attribute__((ext_vector_type(4))) float f32x4;

// ---------------- ws layout ----------------
// [0,32)            counts[8] int
// [512]             map_total int
// [516,804)         slot_e[72] int
// [804,1092)        slot_toff[72] int
// [4096,135168)     entries[8][4096] int   value=(token<<1)|slot
// [135168,167936)   tk_idx[4096][2] int
// [167936,200704)   tk_w[4096][2] float
// fast path only:
// [262144,17039360)   xbf [4096][2048] bf16 (flat row-major)
// [17039360,84148224) WeT_tiled: slab s=(e*16+ntile)*64+k0 of 4096 bf16 (8KB),
//                     within slab elem(n,k)= (n>>4)*512 + ((k>>3)*16+(n&15))*8 + (k&7)
#define WS_COUNTS   0
#define WS_MAPTOT   512
#define WS_SLOTE    516
#define WS_SLOTOFF  804
#define WS_ENTRIES  4096
#define WS_TKIDX    135168
#define WS_TKW      167936
#define WS_XBF      262144
#define WS_WET      17039360
#define WS_BIG_NEED 84148224ULL

__device__ __forceinline__ void gload16(const void* g, void* l) {
  __builtin_amdgcn_global_load_lds(
      (const __attribute__((address_space(1))) void*)g,
      (__attribute__((address_space(3))) void*)l, 16, 0, 0);
}

__global__ void zero_counts(int* counts) {
  if (threadIdx.x < E_NUM) counts[threadIdx.x] = 0;
}

// One wave per token. fp64 accumulation so top-2 ordering matches np ref.
__global__ void gating_kernel(const float* __restrict__ x,
                              const float* __restrict__ Wg,
                              const float* __restrict__ bg,
                              int* counts, int* entries,
                              int* tk_idx, float* tk_w) {
  int gtid = blockIdx.x * blockDim.x + threadIdx.x;
  int b = gtid >> 6;
  int lane = threadIdx.x & 63;
  if (b >= B_TOK) return;
  const float* xrow = x + (size_t)b * D_DIM;

  double acc[E_NUM];
#pragma unroll
  for (int e = 0; e < E_NUM; e++) acc[e] = 0.0;

#pragma unroll
  for (int i = 0; i < 8; i++) {
    int d0 = i * 256 + lane * 4;
    f32x4 xv = *(const f32x4*)(xrow + d0);
#pragma unroll
    for (int j = 0; j < 4; j++) {
      double xf = (double)xv[j];
      f32x4 w0 = *(const f32x4*)(Wg + (size_t)(d0 + j) * E_NUM);
      f32x4 w1 = *(const f32x4*)(Wg + (size_t)(d0 + j) * E_NUM + 4);
#pragma unroll
      for (int e = 0; e < 4; e++) acc[e] += xf * (double)w0[e];
#pragma unroll
      for (int e = 0; e < 4; e++) acc[4 + e] += xf * (double)w1[e];
    }
  }
#pragma unroll
  for (int e = 0; e < E_NUM; e++) {
    double v = acc[e];
#pragma unroll
    for (int off = 32; off >= 1; off >>= 1) v += __shfl_xor(v, off, 64);
    acc[e] = v;
  }

  if (lane == 0) {
    double lg[E_NUM];
#pragma unroll
    for (int e = 0; e < E_NUM; e++) lg[e] = acc[e] + (double)bg[e];
    int i0 = 0; double v0 = lg[0];
#pragma unroll
    for (int e = 1; e < E_NUM; e++) if (lg[e] > v0) { v0 = lg[e]; i0 = e; }
    int i1 = -1; double v1 = -1e300;
#pragma unroll
    for (int e = 0; e < E_NUM; e++)
      if (e != i0 && lg[e] > v1) { v1 = lg[e]; i1 = e; }
    double m = v0;
    double den = 0.0, p0 = 0.0, p1 = 0.0;
#pragma unroll
    for (int e = 0; e < E_NUM; e++) {
      double pe = exp(lg[e] - m);
      den += pe;
      if (e == i0) p0 = pe;
      if (e == i1) p1 = pe;
    }
    tk_idx[2 * b] = i0;
    tk_idx[2 * b + 1] = i1;
    tk_w[2 * b] = (float)(p0 / den);
    tk_w[2 * b + 1] = (float)(p1 / den);
    int q0 = atomicAdd(&counts[i0], 1);
    entries[i0 * B_TOK + q0] = (b << 1);
    int q1 = atomicAdd(&counts[i1], 1);
    entries[i1 * B_TOK + q1] = (b << 1) | 1;
  }
}

// slot -> (expert, tile offset) map; single thread, <=72 iters
__global__ void tile_map_kernel(const int* __restrict__ counts, int* map_total,
                                int* slot_e, int* slot_toff) {
  if (threadIdx.x == 0) {
    int tot = 0;
    for (int e = 0; e < E_NUM; e++) {
      int t = (counts[e] + 127) >> 7;
      for (int i = 0; i < t; i++) { slot_e[tot + i] = e; slot_toff[tot + i] = tot; }
      tot += t;
    }
    *map_total = tot;
  }
}

// out[b][h] = w0*be[e0][h] + w1*be[e1][h]  (overwrites poison; GEMM atomics add on top)
__global__ void prefill_kernel(const float* __restrict__ be,
                               const int* __restrict__ tk_idx,
                               const float* __restrict__ tk_w,
                               float* __restrict__ out) {
  int idx = blockIdx.x * blockDim.x + threadIdx.x;
  int b = idx >> 9;
  int hc = (idx & 511) * 4;
  int e0 = tk_idx[2 * b], e1 = tk_idx[2 * b + 1];
  float w0 = tk_w[2 * b], w1 = tk_w[2 * b + 1];
  f32x4 b0 = *(const f32x4*)(be + (size_t)e0 * H_DIM + hc);
  f32x4 b1 = *(const f32x4*)(be + (size_t)e1 * H_DIM + hc);
  f32x4 o;
#pragma unroll
  for (int j = 0; j < 4; j++) o[j] = w0 * b0[j] + w1 * b1[j];
  *(f32x4*)(out + (size_t)b * H_DIM + hc) = o;
}

__global__ void xcvt_kernel(const float* __restrict__ x, bf16* __restrict__ xbf) {
  int idx = blockIdx.x * blockDim.x + threadIdx.x;  // B*D/8 threads
  f32x4 a = *(const f32x4*)(x + (size_t)idx * 8);
  f32x4 c = *(const f32x4*)(x + (size_t)idx * 8 + 4);
  bf16x8 o;
#pragma unroll
  for (int j = 0; j < 4; j++) { o[j] = (bf16)a[j]; o[4 + j] = (bf16)c[j]; }
  *(bf16x8*)(xbf + (size_t)idx * 8) = o;
}

// We[e][d][h] fp32 -> WeT_tiled slabs (bf16, MFMA-fragment image).
// slab s=(e*16+ntile)*64+k0 (4096 elems); elem(n,k)=(n>>4)*512+((k>>3)*16+(n&15))*8+(k&7)
__global__ void transpose_cvt_we(const float* __restrict__ We, bf16* __restrict__ WeT) {
  __shared__ __align__(16) float tile[64][65];
  int e = blockIdx.z;
  int h0 = blockIdx.x * 64, d0 = blockIdx.y * 64;
  int t = threadIdx.x;
  int dr = t >> 2, hc = (t & 3) * 16;
  const float* src = We + ((size_t)e * D_DIM + d0 + dr) * H_DIM + h0 + hc;
#pragma unroll
  for (int i = 0; i < 4; i++)
    *(f32x4*)(&tile[dr][hc + 4 * i]) = *(const f32x4*)(src + 4 * i);
  __syncthreads();
  int hh = t >> 3, dp = (t & 7) * 8;
#pragma unroll
  for (int s = 0; s < 2; s++) {
    int h = hh + 32 * s;
    bf16x8 v;
#pragma unroll
    for (int j = 0; j < 8; j++) v[j] = (bf16)tile[dp + j][h];
    int gh = h0 + h, gd = d0 + dp;
    int ntile = gh >> 7, n = gh & 127;
    int k0 = gd >> 5, kin = gd & 31;        // kin multiple of 8
    size_t slab = ((size_t)((e * 16 + ntile) * 64 + k0)) * 4096;
    int off = (n >> 4) * 512 + ((kin >> 3) * 16 + (n & 15)) * 8;
    *(bf16x8*)(WeT + slab + off) = v;       // 16B contiguous (j = k&7)
  }
}

// Bucketed GEMM, 128x128 tile, BK=32, distance-2 pipeline, 3 LDS buffers.
// Grid 1-D: bid = slot*16 + ntile  -> XCD = bid%8 = ntile%8 (B-slab L2 locality).
// B staging: 4 x 1KB fully contiguous loads/iter from WeT_tiled slabs
//            (per-lane source addr = slab + chunk + lane*16B  <-- round-4 fix).
// A staging: gathered token rows from flat xbf (16x64B segments per load).
__global__ __launch_bounds__(256) void moe_gemm_fast(
    const bf16* __restrict__ xbf, const bf16* __restrict__ WeT,
    const int* __restrict__ counts, const int* __restrict__ entries,
    const int* __restrict__ map_total, const int* __restrict__ slot_e,
    const int* __restrict__ slot_toff,
    const float* __restrict__ tk_w, float* __restrict__ out) {
  __shared__ __align__(16) bf16 As_s[3 * 4096];
  __shared__ __align__(16) bf16 Bs_s[3 * 4096];
  int bid = blockIdx.x;
  int slot = bid >> 4, ntile = bid & 15;
  if (slot >= *map_total) return;
  int e = slot_e[slot];
  int mtile = slot - slot_toff[slot];
  int cnt = counts[e];
  int n0 = ntile * 128;
  int tid = threadIdx.x, lane = tid & 63, w = tid >> 6;
  int r = lane & 15, q = lane >> 4;
  const int* ereg = entries + e * B_TOK;
  const bf16* wet_nt = WeT + ((size_t)(e * 16 + ntile) * 64) * 4096;

  const bf16* srcA[2];
  const bf16* srcB[2];           // per-lane source addresses (round-4 bugfix)
  int chunk_off[2];
#pragma unroll
  for (int j = 0; j < 2; j++) {
    int ci = w * 2 + j;
    int m = mtile * 128 + 16 * ci + r;
    int tok = ereg[min(m, cnt - 1)] >> 1;
    srcA[j] = xbf + (size_t)tok * D_DIM + 8 * q;
    chunk_off[j] = ci * 512;               // elements
    srcB[j] = wet_nt + chunk_off[j] + lane * 8;  // lane*16B within slab
  }
  int wm4 = (w & 1) * 4, wn4 = (w >> 1) * 4;

  f32x4 acc[4][4];
#pragma unroll
  for (int i = 0; i < 4; i++)
#pragma unroll
    for (int j = 0; j < 4; j++) acc[i][j] = (f32x4){0.f, 0.f, 0.f, 0.f};

  // prologue: tiles 0,1  (slab stride = 4096 elements = 8KB)
#pragma unroll
  for (int p = 0; p < 2; p++) {
#pragma unroll
    for (int j = 0; j < 2; j++) {
      gload16(srcA[j] + p * 32, As_s + p * 4096 + chunk_off[j]);
      gload16(srcB[j] + p * 4096, Bs_s + p * 4096 + chunk_off[j]);
    }
  }

  int pc = 0, pb = 2;
  for (int it = 0; it < 63; it++) {
    // vmcnt(4): tile-it's 4 loads done; barrier: all waves' done + buf[pb] free
    asm volatile("s_waitcnt vmcnt(4)\n\ts_barrier" ::: "memory");
    if (it < 62) {
      int kk = (it + 2) * 32;
#pragma unroll
      for (int j = 0; j < 2; j++) {
        gload16(srcA[j] + kk, As_s + pb * 4096 + chunk_off[j]);
        gload16(srcB[j] + (size_t)(it + 2) * 4096, Bs_s + pb * 4096 + chunk_off[j]);
      }
    }
    {
      const bf16* Ab = As_s + pc * 4096;
      const bf16* Bb = Bs_s + pc * 4096;
      bf16x8 af[4], bfr[4];
#pragma unroll
      for (int i = 0; i < 4; i++)
        af[i] = *(const bf16x8*)(Ab + (wm4 + i) * 512 + lane * 8);
#pragma unroll
      for (int j = 0; j < 4; j++)
        bfr[j] = *(const bf16x8*)(Bb + (wn4 + j) * 512 + lane * 8);
#pragma unroll
      for (int i = 0; i < 4; i++)
#pragma unroll
        for (int j = 0; j < 4; j++)
          acc[i][j] = __builtin_amdgcn_mfma_f32_16x16x32_bf16(af[i], bfr[j],
                                                              acc[i][j], 0, 0, 0);
    }
    pc = (pc == 2) ? 0 : pc + 1;
    pb = (pb == 2) ? 0 : pb + 1;
  }
  asm volatile("s_waitcnt vmcnt(0)\n\ts_barrier" ::: "memory");
  {
    const bf16* Ab = As_s + pc * 4096;
    const bf16* Bb = Bs_s + pc * 4096;
    bf16x8 af[4], bfr[4];
#pragma unroll
    for (int i = 0; i < 4; i++)
      af[i] = *(const bf16x8*)(Ab + (wm4 + i) * 512 + lane * 8);
#pragma unroll
    for (int j = 0; j < 4; j++)
      bfr[j] = *(const bf16x8*)(Bb + (wn4 + j) * 512 + lane * 8);
#pragma unroll
    for (int i = 0; i < 4; i++)
#pragma unroll
      for (int j = 0; j < 4; j++)
        acc[i][j] = __builtin_amdgcn_mfma_f32_16x16x32_bf16(af[i], bfr[j],
                                                            acc[i][j], 0, 0, 0);
  }

  int base_r = mtile * 128, wm = (w & 1) * 64, wn = (w >> 1) * 64;
#pragma unroll
  for (int i = 0; i < 4; i++)
#pragma unroll
    for (int reg = 0; reg < 4; reg++) {
      int rg = base_r + wm + 16 * i + q * 4 + reg;
      if (rg < cnt) {
        int ent = ereg[rg];
        int tok = ent >> 1, slotk = ent & 1;
        float wgt = tk_w[2 * tok + slotk];
        float* orow = out + (size_t)tok * H_DIM + n0 + wn;
#pragma unroll
        for (int j = 0; j < 4; j++)
          atomicAdd(orow + 16 * j + r, wgt * acc[i][j][reg]);
      }
    }
}

// Small-ws fallback (unchanged structure from round 2, known-correct).
__global__ __launch_bounds__(256) void moe_gemm_slow(
    const float* __restrict__ x, const float* __restrict__ We,
    const int* __restrict__ counts, const int* __restrict__ entries,
    const float* __restrict__ tk_w, float* __restrict__ out) {
  __shared__ __align__(16) bf16 As_f[4096];
  __shared__ __align__(16) bf16 Bs_f[4096];
  __shared__ __align__(16) float Braw[4096];
  int e = blockIdx.y >> 5, mtile = blockIdx.y & 31;
  int cnt = counts[e];
  if (mtile * 128 >= cnt) return;
  int n0 = blockIdx.x * 128;
  int tid = threadIdx.x, lane = tid & 63, w = tid >> 6;
  int r = lane & 15, q = lane >> 4;
  const int* ereg = entries + e * B_TOK;

  const float* srcA[2]; bf16* dstA[2];
#pragma unroll
  for (int s = 0; s < 2; s++) {
    int c = tid + s * 256;
    int ci = c >> 6, qq = (c >> 4) & 3, rr = c & 15;
    int m = mtile * 128 + 16 * ci + rr;
    int tok = ereg[min(m, cnt - 1)] >> 1;
    srcA[s] = x + (size_t)tok * D_DIM + 8 * qq;
    dstA[s] = As_f + c * 8;
  }
  const float* srcBr[4]; float* dstBr[4];
#pragma unroll
  for (int i = 0; i < 4; i++) {
    int row = (w * 4 + i) * 2 + (lane >> 5);
    srcBr[i] = We + ((size_t)e * D_DIM + row) * H_DIM + n0 + (lane & 31) * 4;
    dstBr[i] = Braw + (w * 4 + i) * 256;
  }
  int n2[2], q2[2]; bf16* dstB2[2];
#pragma unroll
  for (int s = 0; s < 2; s++) {
    int c = tid + s * 256;
    n2[s] = 16 * (c >> 6) + (c & 15);
    q2[s] = (c >> 4) & 3;
    dstB2[s] = Bs_f + c * 8;
  }
  int wm4 = (w & 1) * 4, wn4 = (w >> 1) * 4;

  f32x4 acc[4][4];
#pragma unroll
  for (int i = 0; i < 4; i++)
#pragma unroll
    for (int j = 0; j < 4; j++) acc[i][j] = (f32x4){0.f, 0.f, 0.f, 0.f};

  for (int k0 = 0; k0 < D_DIM; k0 += 32) {
    __syncthreads();
#pragma unroll
    for (int i = 0; i < 4; i++)
      gload16(srcBr[i] + (size_t)k0 * H_DIM, dstBr[i]);
#pragma unroll
    for (int s = 0; s < 2; s++) {
      f32x4 a0 = *(const f32x4*)(srcA[s] + k0);
      f32x4 a1 = *(const f32x4*)(srcA[s] + k0 + 4);
      bf16x8 av;
#pragma unroll
      for (int j = 0; j < 4; j++) { av[j] = (bf16)a0[j]; av[4 + j] = (bf16)a1[j]; }
      *(bf16x8*)dstA[s] = av;
    }
    __syncthreads();
#pragma unroll
    for (int s = 0; s < 2; s++) {
      bf16x8 bv;
#pragma unroll
      for (int t2 = 0; t2 < 8; t2++)
        bv[t2] = (bf16)Braw[(8 * q2[s] + t2) * 128 + n2[s]];
      *(bf16x8*)dstB2[s] = bv;
    }
    __syncthreads();
    bf16x8 af[4], bfr[4];
#pragma unroll
    for (int i = 0; i < 4; i++)
      af[i] = *(const bf16x8*)(As_f + (wm4 + i) * 512 + lane * 8);
#pragma unroll
    for (int j = 0; j < 4; j++)
      bfr[j] = *(const bf16x8*)(Bs_f + (wn4 + j) * 512 + lane * 8);
#pragma unroll
    for (int i = 0; i < 4; i++)
#pragma unroll
      for (int j = 0; j < 4; j++)
        acc[i][j] = __builtin_amdgcn_mfma_f32_16x16x32_bf16(af[i], bfr[j],
                                                            acc[i][j], 0, 0, 0);
  }

  int base_r = mtile * 128, wm = (w & 1) * 64, wn = (w >> 1) * 64;
#pragma unroll
  for (int i = 0; i < 4; i++)
#pragma unroll
    for (int reg = 0; reg < 4; reg++) {
      int rg = base_r + wm + 16 * i + q * 4 + reg;
      if (rg < cnt) {
        int ent = ereg[rg];
        int tok = ent >> 1, slotk = ent & 1;
        float wgt = tk_w[2 * tok + slotk];
        float* orow = out + (size_t)tok * H_DIM + n0 + wn;
#pragma unroll
        for (int j = 0; j < 4; j++)
          atomicAdd(orow + 16 * j + r, wgt * acc[i][j][reg]);
      }
    }
}

extern "C" void kernel_launch(void* const* d_in, const int* in_sizes, int n_in,
                              void* d_out, int out_size, void* d_ws, size_t ws_size,
                              hipStream_t stream) {
  const float* x  = (const float*)d_in[0];
  const float* Wg = (const float*)d_in[1];
  const float* bg = (const float*)d_in[2];
  const float* We = (const float*)d_in[3];
  const float* be = (const float*)d_in[4];
  float* out = (float*)d_out;

  char* ws = (char*)d_ws;
  int*   counts   = (int*)(ws + WS_COUNTS);
  int*   map_tot  = (int*)(ws + WS_MAPTOT);
  int*   slot_e   = (int*)(ws + WS_SLOTE);
  int*   slot_off = (int*)(ws + WS_SLOTOFF);
  int*   entries  = (int*)(ws + WS_ENTRIES);
  int*   tk_idx   = (int*)(ws + WS_TKIDX);
  float* tk_w     = (float*)(ws + WS_TKW);
  bf16*  xbf      = (bf16*)(ws + WS_XBF);
  bf16*  WeT      = (bf16*)(ws + WS_WET);

  bool big = (ws_size >= WS_BIG_NEED);

  hipLaunchKernelGGL(zero_counts, dim3(1), dim3(64), 0, stream, counts);
  hipLaunchKernelGGL(gating_kernel, dim3(B_TOK / 4), dim3(256), 0, stream,
                     x, Wg, bg, counts, entries, tk_idx, tk_w);
  hipLaunchKernelGGL(prefill_kernel, dim3(B_TOK * H_DIM / 4 / 256), dim3(256), 0,
                     stream, be, tk_idx, tk_w, out);
  if (big) {
    hipLaunchKernelGGL(tile_map_kernel, dim3(1), dim3(64), 0, stream,
                       counts, map_tot, slot_e, slot_off);
    hipLaunchKernelGGL(xcvt_kernel, dim3(B_TOK * D_DIM / 8 / 256), dim3(256), 0,
                       stream, x, xbf);
    hipLaunchKernelGGL(transpose_cvt_we, dim3(H_DIM / 64, D_DIM / 64, E_NUM),
                       dim3(256), 0, stream, We, WeT);
    hipLaunchKernelGGL(moe_gemm_fast, dim3(MAX_SLOTS * 16), dim3(256), 0, stream,
                       xbf, WeT, counts, entries, map_tot, slot_e, slot_off,
                       tk_w, out);
  } else {
    hipLaunchKernelGGL(moe_gemm_slow, dim3(H_DIM / 128, E_NUM * 32), dim3(256), 0,
                       stream, x, We, counts, entries, tk_w, out);
  }
}